// Round 4
// baseline (168.099 us; speedup 1.0000x reference)
//
#include <hip/hip_runtime.h>
#include <hip/hip_bf16.h>

// SAGAN self-attention, B=4 N=4096 C=64 d=8.
// Kernel 1: projections -> ws bf16: Qb[b][n][8] (pre-scaled log2e), Kb[b][n][8],
//           Vt[b][c][n] (pre-transposed = PV B-frag layout), 16B zero page.
// Kernel 2: flash attention, 512 blocks x 16 waves (1024 thr); wave w owns
//           k-range [w*256, w*256+256) for the block's 32 q-rows (2 q-tiles).
//           Permuted K-gather: S^T MFMA output lands directly in the PV
//           A-fragment layout -> zero cross-lane ops in the hot loop.
//           Per-lane partial lsum; defer-max (T13, tau=8); bf16 LDS merge of
//           the 16 k-split partials (32 waves/CU = HW thread-slot cap).

typedef __attribute__((ext_vector_type(4))) float f32x4;
typedef __attribute__((ext_vector_type(8))) short short8;

#define LOG2E 1.44269504088896340736f

#if __has_builtin(__builtin_amdgcn_exp2f)
#define EXP2(x) __builtin_amdgcn_exp2f(x)
#else
#define EXP2(x) exp2f(x)
#endif

__device__ __forceinline__ unsigned short f2bf(float f) {
    __hip_bfloat16 h = __float2bfloat16(f);
    union { __hip_bfloat16 h; unsigned short u; } cv;
    cv.h = h;
    return cv.u;
}

__device__ __forceinline__ float bf2f(unsigned short u) {
    union { unsigned int i; float f; } cv;
    cv.i = ((unsigned int)u) << 16;
    return cv.f;
}

__device__ __forceinline__ unsigned int pk2bf(float lo, float hi) {
    return (unsigned int)f2bf(lo) | ((unsigned int)f2bf(hi) << 16);
}

// ---------------------------------------------------------------------------
// Projection kernel: 512 blocks x 256 threads, 32 tokens per block.
// ---------------------------------------------------------------------------
__global__ __launch_bounds__(256) void sagan_proj_kernel(
    const float* __restrict__ x,
    const float* __restrict__ Wq, const float* __restrict__ bq,
    const float* __restrict__ Wk, const float* __restrict__ bk,
    const float* __restrict__ Wv, const float* __restrict__ bv,
    unsigned short* __restrict__ Qb, unsigned short* __restrict__ Kb,
    unsigned short* __restrict__ Vt, unsigned short* __restrict__ zp)
{
    __shared__ float xs[32][68];   // +4 pad: conflict-free strided reads
    const int tid = threadIdx.x;
    const int blk = blockIdx.x;          // 0..511
    const int tglob0 = blk << 5;         // first global token of this block
    const int b  = tglob0 >> 12;         // batch (N=4096 per batch)
    const int nb = tglob0 & 4095;        // n base within batch

    if (blk == 0 && tid < 8) zp[tid] = 0;   // 16B zero page for flash K pad

    // stage x tile [32 tokens][64 ch]: 8 floats per thread
    {
        const int t = tid >> 3, q8 = tid & 7;
        const float* src = x + (size_t)(tglob0 + t) * 64 + q8 * 8;
        *(f32x4*)&xs[t][q8 * 8]     = *(const f32x4*)(src);
        *(f32x4*)&xs[t][q8 * 8 + 4] = *(const f32x4*)(src + 4);
    }
    __syncthreads();

    // ---- V projection: thread = (channel c = tid&63, group tg = tid>>6) ----
    {
        const int c  = tid & 63;
        const int tg = tid >> 6;             // 0..3
        float wcol[64];
        #pragma unroll
        for (int cc = 0; cc < 64; ++cc) wcol[cc] = Wv[cc * 64 + c];
        const float bvc = bv[c];
        unsigned int wv[4];
        #pragma unroll
        for (int j = 0; j < 8; ++j) {
            const int tok = tg * 8 + j;       // wave-uniform -> LDS broadcast
            float acc = bvc;
            #pragma unroll
            for (int c4 = 0; c4 < 16; ++c4) {
                f32x4 xv = *(const f32x4*)&xs[tok][c4 * 4];
                acc += xv[0] * wcol[c4 * 4 + 0] + xv[1] * wcol[c4 * 4 + 1]
                     + xv[2] * wcol[c4 * 4 + 2] + xv[3] * wcol[c4 * 4 + 3];
            }
            if (j & 1) wv[j >> 1] |= ((unsigned int)f2bf(acc)) << 16;
            else       wv[j >> 1]  =  (unsigned int)f2bf(acc);
        }
        unsigned short* dst = Vt + ((size_t)(b * 64 + c) * 4096) + nb + tg * 8;
        *(uint4*)dst = make_uint4(wv[0], wv[1], wv[2], wv[3]);
    }

    // ---- Q/K projections: thread = (token = tid>>3, d = tid&7) ----
    {
        const int tok = tid >> 3;
        const int dd  = tid & 7;
        float q0 = bq[dd];
        float k0 = bk[dd];
        #pragma unroll
        for (int cc = 0; cc < 64; ++cc) {
            const float xv = xs[tok][cc];
            q0 += xv * Wq[cc * 8 + dd];
            k0 += xv * Wk[cc * 8 + dd];
        }
        const size_t toff = (size_t)(tglob0 + tok) * 8 + dd;
        Qb[toff] = f2bf(q0 * LOG2E);    // fold log2(e): softmax uses exp2
        Kb[toff] = f2bf(k0);
    }
}

// ---------------------------------------------------------------------------
// Flash attention: grid = B*N/32 = 512 blocks, 1024 threads (16 waves).
// Wave w: k in [w*256, w*256+256) for 32 q-rows (2 MFMA q-tiles).
// Permuted K-gather: tile0 A-row r <- K[kt + (r>>2)*8 + (r&3)], tile1 +4.
// S^T output lane (g,ql) holds S[q=ql][k = kt+g*8+{0..7}] across the two
// tiles == the PV A-fragment element order. Zero shuffles in the hot loop.
// ---------------------------------------------------------------------------
__global__ __launch_bounds__(1024, 8) void sagan_flash_kernel(
    const unsigned short* __restrict__ Qb, const unsigned short* __restrict__ Kb,
    const unsigned short* __restrict__ Vt, const unsigned short* __restrict__ zp,
    const float* __restrict__ x, const float* __restrict__ gamma_p,
    float* __restrict__ out)
{
    __shared__ unsigned short sacc[16][32][72];  // [wave][q-row][col] bf16 72KB
    __shared__ float sml[16][2][32];             // [wave][m|l][q-row]    4KB

    const int tid  = threadIdx.x;
    const int lane = tid & 63;
    const int w    = tid >> 6;               // wave id = k-split index 0..15
    const int g    = lane >> 4;
    const int ql   = lane & 15;
    const int blk  = blockIdx.x;
    const int b    = blk >> 7;               // 128 blocks per batch
    const int qbase = (blk & 127) << 5;      // 32 q-rows per block

    const unsigned short* Kbase = Kb + (size_t)b * (4096 * 8);
    const unsigned short* Vbase = Vt + (size_t)b * (64 * 4096);

    const short8 zfrag = {0, 0, 0, 0, 0, 0, 0, 0};
    short8 qf0, qf1;                         // B-operand: Q[q=ql][d], g>0 pad
    {
        short8 a = *(const short8*)(Qb + (size_t)(b * 4096 + qbase + ql) * 8);
        short8 c = *(const short8*)(Qb + (size_t)(b * 4096 + qbase + 16 + ql) * 8);
        qf0 = (g == 0) ? a : zfrag;
        qf1 = (g == 0) ? c : zfrag;
    }

    const int kt0 = w << 8;                  // 256 k per wave

    // Permuted K pointers; g!=0 lanes read the zero page (stride 0).
    const unsigned short* kp0;
    const unsigned short* kp1;
    int kstep;
    if (g == 0) {
        const int kperm = ((ql >> 2) << 3) | (ql & 3);
        kp0 = Kbase + (size_t)(kt0 + kperm) * 8;
        kp1 = kp0 + 32;                      // +4 tokens
        kstep = 256;                         // 32 tokens * 8 shorts
    } else {
        kp0 = zp; kp1 = zp; kstep = 0;
    }

    // V B-operand rows: lane (g,ql) reads Vt[c=ct*16+ql][kt + g*8 .. +8)
    const unsigned short* vp0 = Vbase + (size_t)ql * 4096 + kt0 + g * 8;
    const unsigned short* vp1 = vp0 + 16 * 4096;
    const unsigned short* vp2 = vp0 + 32 * 4096;
    const unsigned short* vp3 = vp0 + 48 * 4096;

    f32x4 acc00 = {0.f,0.f,0.f,0.f}, acc01 = acc00, acc02 = acc00, acc03 = acc00;
    f32x4 acc10 = acc00, acc11 = acc00, acc12 = acc00, acc13 = acc00;
    float m0 = -1e30f, m1 = -1e30f, l0 = 0.f, l1 = 0.f;

    for (int it = 0; it < 8; ++it) {
        const short8 ka0 = *(const short8*)kp0;
        const short8 ka1 = *(const short8*)kp1;
        kp0 += kstep; kp1 += kstep;
        const short8 vf0 = *(const short8*)vp0; vp0 += 32;
        const short8 vf1 = *(const short8*)vp1; vp1 += 32;
        const short8 vf2 = *(const short8*)vp2; vp2 += 32;
        const short8 vf3 = *(const short8*)vp3; vp3 += 32;

        const f32x4 zc = {0.f, 0.f, 0.f, 0.f};

        // ================= q-tile 0 =================
        {
            f32x4 s0 = __builtin_amdgcn_mfma_f32_16x16x32_bf16(ka0, qf0, zc, 0, 0, 0);
            f32x4 s1 = __builtin_amdgcn_mfma_f32_16x16x32_bf16(ka1, qf0, zc, 0, 0, 0);
            // lane holds S[q=ql][k = kt + g*8 + {0..3}] (s0) and {4..7} (s1)
            float cm = fmaxf(fmaxf(fmaxf(s0[0], s0[1]), fmaxf(s0[2], s0[3])),
                             fmaxf(fmaxf(s1[0], s1[1]), fmaxf(s1[2], s1[3])));
            if (!__all(cm - m0 <= 8.f)) {
                float t = fmaxf(cm, __shfl_xor(cm, 16));
                t = fmaxf(t, __shfl_xor(t, 32));
                const float mn = fmaxf(m0, t);
                const float c = EXP2(m0 - mn);
                float cr[4];
                #pragma unroll
                for (int r = 0; r < 4; ++r) cr[r] = __shfl(c, (g << 2) | r);
                #pragma unroll
                for (int r = 0; r < 4; ++r) {
                    acc00[r] *= cr[r]; acc01[r] *= cr[r];
                    acc02[r] *= cr[r]; acc03[r] *= cr[r];
                }
                l0 *= c; m0 = mn;
            }
            float p[8];
            #pragma unroll
            for (int r = 0; r < 4; ++r) {
                p[r]     = EXP2(s0[r] - m0);
                p[4 + r] = EXP2(s1[r] - m0);
            }
            l0 += ((p[0] + p[1]) + (p[2] + p[3])) + ((p[4] + p[5]) + (p[6] + p[7]));
            union { unsigned int wd[4]; short8 v; } pa;
            pa.wd[0] = pk2bf(p[0], p[1]); pa.wd[1] = pk2bf(p[2], p[3]);
            pa.wd[2] = pk2bf(p[4], p[5]); pa.wd[3] = pk2bf(p[6], p[7]);
            acc00 = __builtin_amdgcn_mfma_f32_16x16x32_bf16(pa.v, vf0, acc00, 0, 0, 0);
            acc01 = __builtin_amdgcn_mfma_f32_16x16x32_bf16(pa.v, vf1, acc01, 0, 0, 0);
            acc02 = __builtin_amdgcn_mfma_f32_16x16x32_bf16(pa.v, vf2, acc02, 0, 0, 0);
            acc03 = __builtin_amdgcn_mfma_f32_16x16x32_bf16(pa.v, vf3, acc03, 0, 0, 0);
        }

        // ================= q-tile 1 =================
        {
            f32x4 s0 = __builtin_amdgcn_mfma_f32_16x16x32_bf16(ka0, qf1, zc, 0, 0, 0);
            f32x4 s1 = __builtin_amdgcn_mfma_f32_16x16x32_bf16(ka1, qf1, zc, 0, 0, 0);
            float cm = fmaxf(fmaxf(fmaxf(s0[0], s0[1]), fmaxf(s0[2], s0[3])),
                             fmaxf(fmaxf(s1[0], s1[1]), fmaxf(s1[2], s1[3])));
            if (!__all(cm - m1 <= 8.f)) {
                float t = fmaxf(cm, __shfl_xor(cm, 16));
                t = fmaxf(t, __shfl_xor(t, 32));
                const float mn = fmaxf(m1, t);
                const float c = EXP2(m1 - mn);
                float cr[4];
                #pragma unroll
                for (int r = 0; r < 4; ++r) cr[r] = __shfl(c, (g << 2) | r);
                #pragma unroll
                for (int r = 0; r < 4; ++r) {
                    acc10[r] *= cr[r]; acc11[r] *= cr[r];
                    acc12[r] *= cr[r]; acc13[r] *= cr[r];
                }
                l1 *= c; m1 = mn;
            }
            float p[8];
            #pragma unroll
            for (int r = 0; r < 4; ++r) {
                p[r]     = EXP2(s0[r] - m1);
                p[4 + r] = EXP2(s1[r] - m1);
            }
            l1 += ((p[0] + p[1]) + (p[2] + p[3])) + ((p[4] + p[5]) + (p[6] + p[7]));
            union { unsigned int wd[4]; short8 v; } pa;
            pa.wd[0] = pk2bf(p[0], p[1]); pa.wd[1] = pk2bf(p[2], p[3]);
            pa.wd[2] = pk2bf(p[4], p[5]); pa.wd[3] = pk2bf(p[6], p[7]);
            acc10 = __builtin_amdgcn_mfma_f32_16x16x32_bf16(pa.v, vf0, acc10, 0, 0, 0);
            acc11 = __builtin_amdgcn_mfma_f32_16x16x32_bf16(pa.v, vf1, acc11, 0, 0, 0);
            acc12 = __builtin_amdgcn_mfma_f32_16x16x32_bf16(pa.v, vf2, acc12, 0, 0, 0);
            acc13 = __builtin_amdgcn_mfma_f32_16x16x32_bf16(pa.v, vf3, acc13, 0, 0, 0);
        }
    }

    // ---- per-wave finalize: complete row-sums (once, not per chunk) ----
    l0 += __shfl_xor(l0, 16); l0 += __shfl_xor(l0, 32);
    l1 += __shfl_xor(l1, 16); l1 += __shfl_xor(l1, 32);

    #pragma unroll
    for (int r = 0; r < 4; ++r) {
        const int row = (g << 2) | r;
        unsigned short* d0 = &sacc[w][row][0];
        d0[ql] = f2bf(acc00[r]); d0[16 + ql] = f2bf(acc01[r]);
        d0[32 + ql] = f2bf(acc02[r]); d0[48 + ql] = f2bf(acc03[r]);
        unsigned short* d1 = &sacc[w][16 + row][0];
        d1[ql] = f2bf(acc10[r]); d1[16 + ql] = f2bf(acc11[r]);
        d1[32 + ql] = f2bf(acc12[r]); d1[48 + ql] = f2bf(acc13[r]);
    }
    if (g == 0) {
        sml[w][0][ql] = m0; sml[w][0][16 + ql] = m1;
        sml[w][1][ql] = l0; sml[w][1][16 + ql] = l1;
    }
    __syncthreads();

    // ---- merge 16 k-split partials: thread -> (row = tid>>5, 2 cols) ----
    {
        const int row = tid >> 5;            // 0..31
        const int col = tid & 31;            // 0..31  (handles col, col+32)
        float M = sml[0][0][row];
        #pragma unroll
        for (int ww = 1; ww < 16; ++ww) M = fmaxf(M, sml[ww][0][row]);
        float L = 0.f, O0 = 0.f, O1 = 0.f;
        #pragma unroll
        for (int ww = 0; ww < 16; ++ww) {
            const float sc = EXP2(sml[ww][0][row] - M);
            L += sml[ww][1][row] * sc;
            const unsigned short* s = &sacc[ww][row][0];
            O0 += bf2f(s[col]) * sc;
            O1 += bf2f(s[col + 32]) * sc;
        }
        const float Li = 1.0f / L;
        const float gm = gamma_p[0];
        const size_t rowoff = ((size_t)(b * 4096 + qbase + row)) * 64;
        out[rowoff + col]      = gm * (O0 * Li) + x[rowoff + col];
        out[rowoff + col + 32] = gm * (O1 * Li) + x[rowoff + col + 32];
    }
}

// ---------------------------------------------------------------------------
extern "C" void kernel_launch(void* const* d_in, const int* in_sizes, int n_in,
                              void* d_out, int out_size, void* d_ws, size_t ws_size,
                              hipStream_t stream) {
    const float* x  = (const float*)d_in[0];
    const float* Wq = (const float*)d_in[1];
    const float* bq = (const float*)d_in[2];
    const float* Wk = (const float*)d_in[3];
    const float* bk = (const float*)d_in[4];
    const float* Wv = (const float*)d_in[5];
    const float* bv = (const float*)d_in[6];
    const float* gm = (const float*)d_in[7];
    float* out = (float*)d_out;

    // ws layout (bf16): Qb[4][4096][8] | Kb[4][4096][8] | Vt[4][64][4096] | zp[8]
    unsigned short* Qb = (unsigned short*)d_ws;
    unsigned short* Kb = Qb + 131072;
    unsigned short* Vt = Kb + 131072;
    unsigned short* zp = Vt + 1048576;   // 16B zero page (16B-aligned)

    hipLaunchKernelGGL(sagan_proj_kernel, dim3(512), dim3(256), 0, stream,
                       x, Wq, bq, Wk, bk, Wv, bv, Qb, Kb, Vt, zp);
    hipLaunchKernelGGL(sagan_flash_kernel, dim3(512), dim3(1024), 0, stream,
                       Qb, Kb, Vt, zp, x, gm, out);
}

// Round 5
// 40.936 us; speedup vs baseline: 4.1064x; 4.1064x over previous
//
#include <hip/hip_runtime.h>
#include <hip/hip_bf16.h>

// SAGAN self-attention, B=4 N=4096 C=64 d=8.
// Kernel 1: projections -> ws bf16: Qb[b][n][8] (pre-scaled log2e), Kb[b][n][8],
//           Vt2[b][kchunk][c][32] (k-tiled V-transpose = PV B-frag layout,
//           one base pointer + imm offsets in flash), 16B zero page.
// Kernel 2: flash attention, 512 blocks x 16 waves (1024 thr); wave w owns
//           k-range [w*256, w*256+256) for the block's 32 q-rows (2 q-tiles).
//           Permuted K-gather: S^T MFMA output lands directly in the PV
//           A-fragment layout -> zero cross-lane ops in the hot loop.
//           Per-lane partial lsum; defer-max (T13, tau=8); bf16 LDS merge of
//           the 16 k-split partials. launch_bounds(1024,4): cap 128 so the
//           allocator lands ~56 naturally (round-4's (1024,8) hard-cap=64
//           caused catastrophic scratch spill); #pragma unroll 1 keeps
//           pressure down so HW can still pack 8 waves/SIMD if VGPR<=64.

typedef __attribute__((ext_vector_type(4))) float f32x4;
typedef __attribute__((ext_vector_type(8))) short short8;

#define LOG2E 1.44269504088896340736f

#if __has_builtin(__builtin_amdgcn_exp2f)
#define EXP2(x) __builtin_amdgcn_exp2f(x)
#else
#define EXP2(x) exp2f(x)
#endif

__device__ __forceinline__ unsigned short f2bf(float f) {
    __hip_bfloat16 h = __float2bfloat16(f);
    union { __hip_bfloat16 h; unsigned short u; } cv;
    cv.h = h;
    return cv.u;
}

__device__ __forceinline__ float bf2f(unsigned short u) {
    union { unsigned int i; float f; } cv;
    cv.i = ((unsigned int)u) << 16;
    return cv.f;
}

// VALU-light bf16 pair pack: +0x8000 round bit, then one v_perm_b32 grabs the
// two high halves. (P >= 0, finite -> no NaN/sign corner cases.)
__device__ __forceinline__ unsigned int pkbf_rnd(float lo, float hi) {
    union { float f; unsigned int u; } a, b;
    a.f = lo; b.f = hi;
    const unsigned int ar = a.u + 0x8000u;
    const unsigned int br = b.u + 0x8000u;
    return __builtin_amdgcn_perm(br, ar, 0x07060302u); // [b3 b2 a3 a2]
}

// ---------------------------------------------------------------------------
// Projection kernel: 512 blocks x 256 threads, 32 tokens per block.
// ---------------------------------------------------------------------------
__global__ __launch_bounds__(256) void sagan_proj_kernel(
    const float* __restrict__ x,
    const float* __restrict__ Wq, const float* __restrict__ bq,
    const float* __restrict__ Wk, const float* __restrict__ bk,
    const float* __restrict__ Wv, const float* __restrict__ bv,
    unsigned short* __restrict__ Qb, unsigned short* __restrict__ Kb,
    unsigned short* __restrict__ Vt, unsigned short* __restrict__ zp)
{
    __shared__ float xs[32][68];   // +4 pad: conflict-free strided reads
    const int tid = threadIdx.x;
    const int blk = blockIdx.x;          // 0..511
    const int tglob0 = blk << 5;         // first global token of this block
    const int b  = tglob0 >> 12;         // batch (N=4096 per batch)
    const int nb = tglob0 & 4095;        // n base within batch (32-aligned)

    if (blk == 0 && tid < 8) zp[tid] = 0;   // 16B zero page for flash K pad

    // stage x tile [32 tokens][64 ch]: 8 floats per thread
    {
        const int t = tid >> 3, q8 = tid & 7;
        const float* src = x + (size_t)(tglob0 + t) * 64 + q8 * 8;
        *(f32x4*)&xs[t][q8 * 8]     = *(const f32x4*)(src);
        *(f32x4*)&xs[t][q8 * 8 + 4] = *(const f32x4*)(src + 4);
    }
    __syncthreads();

    // ---- V projection: thread = (channel c = tid&63, group tg = tid>>6) ----
    // Vt2[b][kchunk=n>>5][c][n&31]; this block covers exactly chunk nb>>5.
    {
        const int c  = tid & 63;
        const int tg = tid >> 6;             // 0..3
        float wcol[64];
        #pragma unroll
        for (int cc = 0; cc < 64; ++cc) wcol[cc] = Wv[cc * 64 + c];
        const float bvc = bv[c];
        unsigned int wv[4];
        #pragma unroll
        for (int j = 0; j < 8; ++j) {
            const int tok = tg * 8 + j;       // wave-uniform -> LDS broadcast
            float acc = bvc;
            #pragma unroll
            for (int c4 = 0; c4 < 16; ++c4) {
                f32x4 xv = *(const f32x4*)&xs[tok][c4 * 4];
                acc += xv[0] * wcol[c4 * 4 + 0] + xv[1] * wcol[c4 * 4 + 1]
                     + xv[2] * wcol[c4 * 4 + 2] + xv[3] * wcol[c4 * 4 + 3];
            }
            if (j & 1) wv[j >> 1] |= ((unsigned int)f2bf(acc)) << 16;
            else       wv[j >> 1]  =  (unsigned int)f2bf(acc);
        }
        unsigned short* dst = Vt + ((size_t)((b * 128 + (nb >> 5)) * 64 + c)) * 32
                                 + tg * 8;
        *(uint4*)dst = make_uint4(wv[0], wv[1], wv[2], wv[3]);
    }

    // ---- Q/K projections: thread = (token = tid>>3, d = tid&7) ----
    {
        const int tok = tid >> 3;
        const int dd  = tid & 7;
        float q0 = bq[dd];
        float k0 = bk[dd];
        #pragma unroll
        for (int cc = 0; cc < 64; ++cc) {
            const float xv = xs[tok][cc];
            q0 += xv * Wq[cc * 8 + dd];
            k0 += xv * Wk[cc * 8 + dd];
        }
        const size_t toff = (size_t)(tglob0 + tok) * 8 + dd;
        Qb[toff] = f2bf(q0 * LOG2E);    // fold log2(e): softmax uses exp2
        Kb[toff] = f2bf(k0);
    }
}

// ---------------------------------------------------------------------------
// Flash attention: grid = B*N/32 = 512 blocks, 1024 threads (16 waves).
// Wave w: k in [w*256, w*256+256) for 32 q-rows (2 MFMA q-tiles).
// Permuted K-gather: tile0 A-row r <- K[kt + (r>>2)*8 + (r&3)], tile1 +4.
// S^T output lane (g,ql) holds S[q=ql][k = kt+g*8+{0..7}] across the two
// tiles == the PV A-fragment element order. Zero shuffles in the hot loop.
// ---------------------------------------------------------------------------
__global__ __launch_bounds__(1024, 4) void sagan_flash_kernel(
    const unsigned short* __restrict__ Qb, const unsigned short* __restrict__ Kb,
    const unsigned short* __restrict__ Vt, const unsigned short* __restrict__ zp,
    const float* __restrict__ x, const float* __restrict__ gamma_p,
    float* __restrict__ out)
{
    __shared__ unsigned short sacc[16][32][72];  // [wave][q-row][col] bf16 72KB
    __shared__ float sml[16][2][32];             // [wave][m|l][q-row]    4KB

    const int tid  = threadIdx.x;
    const int lane = tid & 63;
    const int w    = tid >> 6;               // wave id = k-split index 0..15
    const int g    = lane >> 4;
    const int ql   = lane & 15;
    const int blk  = blockIdx.x;
    const int b    = blk >> 7;               // 128 blocks per batch
    const int qbase = (blk & 127) << 5;      // 32 q-rows per block

    const unsigned short* Kbase = Kb + (size_t)b * (4096 * 8);

    const short8 zfrag = {0, 0, 0, 0, 0, 0, 0, 0};
    short8 qf0, qf1;                         // B-operand: Q[q=ql][d], g>0 pad
    {
        short8 a = *(const short8*)(Qb + (size_t)(b * 4096 + qbase + ql) * 8);
        short8 c = *(const short8*)(Qb + (size_t)(b * 4096 + qbase + 16 + ql) * 8);
        qf0 = (g == 0) ? a : zfrag;
        qf1 = (g == 0) ? c : zfrag;
    }

    const int kt0 = w << 8;                  // 256 k per wave

    // Permuted K pointer; g!=0 lanes read the zero page (stride 0).
    const unsigned short* kp0;
    int kstep;
    if (g == 0) {
        const int kperm = ((ql >> 2) << 3) | (ql & 3);
        kp0 = Kbase + (size_t)(kt0 + kperm) * 8;
        kstep = 256;                         // 32 tokens * 8 shorts
    } else {
        kp0 = zp; kstep = 0;
    }

    // V: Vt2[b][chunk][c][32]; one pointer, c-groups at +512 shorts imm.
    const unsigned short* vp = Vt + ((size_t)(b * 128 + w * 8) * 64) * 32
                                  + ql * 32 + g * 8;

    f32x4 acc00 = {0.f,0.f,0.f,0.f}, acc01 = acc00, acc02 = acc00, acc03 = acc00;
    f32x4 acc10 = acc00, acc11 = acc00, acc12 = acc00, acc13 = acc00;
    float m0 = -1e30f, m1 = -1e30f, l0 = 0.f, l1 = 0.f;

    #pragma unroll 1
    for (int it = 0; it < 8; ++it) {
        const short8 ka0 = *(const short8*)kp0;
        const short8 ka1 = *(const short8*)(kp0 + 32);   // imm offset:64B
        kp0 += kstep;
        const short8 vf0 = *(const short8*)(vp);
        const short8 vf1 = *(const short8*)(vp + 512);   // imm offset:1024B
        const short8 vf2 = *(const short8*)(vp + 1024);  // imm offset:2048B
        const short8 vf3 = *(const short8*)(vp + 1536);  // imm offset:3072B
        vp += 2048;

        const f32x4 zc = {0.f, 0.f, 0.f, 0.f};

        // ================= q-tile 0 =================
        {
            f32x4 s0 = __builtin_amdgcn_mfma_f32_16x16x32_bf16(ka0, qf0, zc, 0, 0, 0);
            f32x4 s1 = __builtin_amdgcn_mfma_f32_16x16x32_bf16(ka1, qf0, zc, 0, 0, 0);
            // lane holds S[q=ql][k = kt + g*8 + {0..3}] (s0) and {4..7} (s1)
            float cm = fmaxf(fmaxf(fmaxf(s0[0], s0[1]), fmaxf(s0[2], s0[3])),
                             fmaxf(fmaxf(s1[0], s1[1]), fmaxf(s1[2], s1[3])));
            if (!__all(cm - m0 <= 8.f)) {
                float t = fmaxf(cm, __shfl_xor(cm, 16));
                t = fmaxf(t, __shfl_xor(t, 32));
                const float mn = fmaxf(m0, t);
                const float c = EXP2(m0 - mn);
                float cr[4];
                #pragma unroll
                for (int r = 0; r < 4; ++r) cr[r] = __shfl(c, (g << 2) | r);
                #pragma unroll
                for (int r = 0; r < 4; ++r) {
                    acc00[r] *= cr[r]; acc01[r] *= cr[r];
                    acc02[r] *= cr[r]; acc03[r] *= cr[r];
                }
                l0 *= c; m0 = mn;
            }
            float p[8];
            #pragma unroll
            for (int r = 0; r < 4; ++r) {
                p[r]     = EXP2(s0[r] - m0);
                p[4 + r] = EXP2(s1[r] - m0);
            }
            l0 += ((p[0] + p[1]) + (p[2] + p[3])) + ((p[4] + p[5]) + (p[6] + p[7]));
            union { unsigned int wd[4]; short8 v; } pa;
            pa.wd[0] = pkbf_rnd(p[0], p[1]); pa.wd[1] = pkbf_rnd(p[2], p[3]);
            pa.wd[2] = pkbf_rnd(p[4], p[5]); pa.wd[3] = pkbf_rnd(p[6], p[7]);
            acc00 = __builtin_amdgcn_mfma_f32_16x16x32_bf16(pa.v, vf0, acc00, 0, 0, 0);
            acc01 = __builtin_amdgcn_mfma_f32_16x16x32_bf16(pa.v, vf1, acc01, 0, 0, 0);
            acc02 = __builtin_amdgcn_mfma_f32_16x16x32_bf16(pa.v, vf2, acc02, 0, 0, 0);
            acc03 = __builtin_amdgcn_mfma_f32_16x16x32_bf16(pa.v, vf3, acc03, 0, 0, 0);
        }

        // ================= q-tile 1 =================
        {
            f32x4 s0 = __builtin_amdgcn_mfma_f32_16x16x32_bf16(ka0, qf1, zc, 0, 0, 0);
            f32x4 s1 = __builtin_amdgcn_mfma_f32_16x16x32_bf16(ka1, qf1, zc, 0, 0, 0);
            float cm = fmaxf(fmaxf(fmaxf(s0[0], s0[1]), fmaxf(s0[2], s0[3])),
                             fmaxf(fmaxf(s1[0], s1[1]), fmaxf(s1[2], s1[3])));
            if (!__all(cm - m1 <= 8.f)) {
                float t = fmaxf(cm, __shfl_xor(cm, 16));
                t = fmaxf(t, __shfl_xor(t, 32));
                const float mn = fmaxf(m1, t);
                const float c = EXP2(m1 - mn);
                float cr[4];
                #pragma unroll
                for (int r = 0; r < 4; ++r) cr[r] = __shfl(c, (g << 2) | r);
                #pragma unroll
                for (int r = 0; r < 4; ++r) {
                    acc10[r] *= cr[r]; acc11[r] *= cr[r];
                    acc12[r] *= cr[r]; acc13[r] *= cr[r];
                }
                l1 *= c; m1 = mn;
            }
            float p[8];
            #pragma unroll
            for (int r = 0; r < 4; ++r) {
                p[r]     = EXP2(s0[r] - m1);
                p[4 + r] = EXP2(s1[r] - m1);
            }
            l1 += ((p[0] + p[1]) + (p[2] + p[3])) + ((p[4] + p[5]) + (p[6] + p[7]));
            union { unsigned int wd[4]; short8 v; } pa;
            pa.wd[0] = pkbf_rnd(p[0], p[1]); pa.wd[1] = pkbf_rnd(p[2], p[3]);
            pa.wd[2] = pkbf_rnd(p[4], p[5]); pa.wd[3] = pkbf_rnd(p[6], p[7]);
            acc10 = __builtin_amdgcn_mfma_f32_16x16x32_bf16(pa.v, vf0, acc10, 0, 0, 0);
            acc11 = __builtin_amdgcn_mfma_f32_16x16x32_bf16(pa.v, vf1, acc11, 0, 0, 0);
            acc12 = __builtin_amdgcn_mfma_f32_16x16x32_bf16(pa.v, vf2, acc12, 0, 0, 0);
            acc13 = __builtin_amdgcn_mfma_f32_16x16x32_bf16(pa.v, vf3, acc13, 0, 0, 0);
        }
    }

    // ---- per-wave finalize: complete row-sums (once, not per chunk) ----
    l0 += __shfl_xor(l0, 16); l0 += __shfl_xor(l0, 32);
    l1 += __shfl_xor(l1, 16); l1 += __shfl_xor(l1, 32);

    #pragma unroll
    for (int r = 0; r < 4; ++r) {
        const int row = (g << 2) | r;
        unsigned short* d0 = &sacc[w][row][0];
        d0[ql] = f2bf(acc00[r]); d0[16 + ql] = f2bf(acc01[r]);
        d0[32 + ql] = f2bf(acc02[r]); d0[48 + ql] = f2bf(acc03[r]);
        unsigned short* d1 = &sacc[w][16 + row][0];
        d1[ql] = f2bf(acc10[r]); d1[16 + ql] = f2bf(acc11[r]);
        d1[32 + ql] = f2bf(acc12[r]); d1[48 + ql] = f2bf(acc13[r]);
    }
    if (g == 0) {
        sml[w][0][ql] = m0; sml[w][0][16 + ql] = m1;
        sml[w][1][ql] = l0; sml[w][1][16 + ql] = l1;
    }
    __syncthreads();

    // ---- merge 16 k-split partials: thread -> (row = tid>>5, 2 cols) ----
    {
        const int row = tid >> 5;            // 0..31
        const int col = tid & 31;            // 0..31  (handles col, col+32)
        float M = sml[0][0][row];
        #pragma unroll
        for (int ww = 1; ww < 16; ++ww) M = fmaxf(M, sml[ww][0][row]);
        float L = 0.f, O0 = 0.f, O1 = 0.f;
        #pragma unroll
        for (int ww = 0; ww < 16; ++ww) {
            const float sc = EXP2(sml[ww][0][row] - M);
            L += sml[ww][1][row] * sc;
            const unsigned short* s = &sacc[ww][row][0];
            O0 += bf2f(s[col]) * sc;
            O1 += bf2f(s[col + 32]) * sc;
        }
        const float Li = 1.0f / L;
        const float gm = gamma_p[0];
        const size_t rowoff = ((size_t)(b * 4096 + qbase + row)) * 64;
        out[rowoff + col]      = gm * (O0 * Li) + x[rowoff + col];
        out[rowoff + col + 32] = gm * (O1 * Li) + x[rowoff + col + 32];
    }
}

// ---------------------------------------------------------------------------
extern "C" void kernel_launch(void* const* d_in, const int* in_sizes, int n_in,
                              void* d_out, int out_size, void* d_ws, size_t ws_size,
                              hipStream_t stream) {
    const float* x  = (const float*)d_in[0];
    const float* Wq = (const float*)d_in[1];
    const float* bq = (const float*)d_in[2];
    const float* Wk = (const float*)d_in[3];
    const float* bk = (const float*)d_in[4];
    const float* Wv = (const float*)d_in[5];
    const float* bv = (const float*)d_in[6];
    const float* gm = (const float*)d_in[7];
    float* out = (float*)d_out;

    // ws (bf16): Qb[4][4096][8] | Kb[4][4096][8] | Vt2[4][128][64][32] | zp[8]
    unsigned short* Qb = (unsigned short*)d_ws;
    unsigned short* Kb = Qb + 131072;
    unsigned short* Vt = Kb + 131072;
    unsigned short* zp = Vt + 1048576;   // 16B zero page (16B-aligned)

    hipLaunchKernelGGL(sagan_proj_kernel, dim3(512), dim3(256), 0, stream,
                       x, Wq, bq, Wk, bk, Wv, bv, Qb, Kb, Vt, zp);
    hipLaunchKernelGGL(sagan_flash_kernel, dim3(512), dim3(1024), 0, stream,
                       Qb, Kb, Vt, zp, x, gm, out);
}